// Round 9
// baseline (145.824 us; speedup 1.0000x reference)
//
#include <hip/hip_runtime.h>

typedef unsigned short u16;
typedef unsigned int u32;
typedef __bf16 bf16_t;
typedef bf16_t bf16x8 __attribute__((ext_vector_type(8)));
typedef bf16_t bf16x4_t __attribute__((ext_vector_type(4)));
typedef float f32x4 __attribute__((ext_vector_type(4)));
typedef unsigned short ushort8_t __attribute__((ext_vector_type(8)));

#define S_LEN 2048
#define DM 1024
#define NH 16
#define HDIM 64
#define PSTR 80   // attn P row stride in u16
#define TSTR 136  // V-transpose LDS row stride in u16 (272B -> 2-way max, free)

// ---- helpers ----
__device__ __forceinline__ u16 f2b(float f) {
  u32 u = __builtin_bit_cast(u32, f);
  u32 r = (u + 0x7FFFu + ((u >> 16) & 1u)) >> 16;  // RNE
  return (u16)r;
}

__device__ __forceinline__ void gload16(const void* g, void* l) {
  __builtin_amdgcn_global_load_lds((const __attribute__((address_space(1))) void*)g,
                                   (__attribute__((address_space(3))) void*)l,
                                   16, 0, 0);
}

__device__ __forceinline__ bf16x8 ld_bf8(const u16* p) {
  return *reinterpret_cast<const bf16x8*>(p);
}

// ---- 64x64 tile staging for attn (row stride `stride` u16), source-swizzled ----
__device__ __forceinline__ void stage_tile256(const u16* __restrict__ base, int stride,
                                              u16* __restrict__ dst, int tid) {
#pragma unroll
  for (int i = 0; i < 2; ++i) {
    int ci = i * 256 + tid;
    int row = ci >> 3, col = ci & 7;
    gload16(base + (size_t)row * stride + ((col ^ (row & 7)) << 3), dst + ci * 8);
  }
}
__device__ __forceinline__ bf16x8 ld_swz64(const u16* lds, int row, int chunk) {
  return ld_bf8(lds + row * 64 + ((chunk ^ (row & 7)) << 3));
}

// ---- 128x32 tile staging for GEMM (64B rows, 4 chunks; swz f(row)=(row>>1)&3) ----
__device__ __forceinline__ void stage_tile32(const u16* __restrict__ base,
                                             u16* __restrict__ dst, int tid) {
#pragma unroll
  for (int i = 0; i < 2; ++i) {
    int ci = i * 256 + tid;
    int row = ci >> 2, ch = ci & 3;
    gload16(base + (size_t)row * DM + ((ch ^ ((row >> 1) & 3)) << 3), dst + ci * 8);
  }
}
__device__ __forceinline__ bf16x8 ld_swz32(const u16* lds, int row, int chunk) {
  return ld_bf8(lds + row * 32 + ((chunk ^ ((row >> 1) & 3)) << 3));
}

// ---- kernel 1: x f32 -> bf16 ----
__global__ __launch_bounds__(256) void k_cvt(const float* __restrict__ in, u16* __restrict__ out) {
  int i = (blockIdx.x * 256 + threadIdx.x) * 4;
  float4 v = *reinterpret_cast<const float4*>(in + i);
  ushort4 o = make_ushort4(f2b(v.x), f2b(v.y), f2b(v.z), f2b(v.w));
  *reinterpret_cast<ushort4*>(out + i) = o;
}

// ---- kernel 2: W [K][N] f32 -> Wt [N][K] bf16 ----
__global__ __launch_bounds__(256) void k_wt(const float* __restrict__ W, u16* __restrict__ Wt) {
  __shared__ float t[32][33];
  int n0 = blockIdx.x * 32, k0 = blockIdx.y * 32;
  int tx = threadIdx.x & 31, ty = threadIdx.x >> 5;
#pragma unroll
  for (int i = 0; i < 32; i += 8)
    t[ty + i][tx] = W[(size_t)(k0 + ty + i) * DM + n0 + tx];
  __syncthreads();
#pragma unroll
  for (int i = 0; i < 32; i += 8)
    Wt[(size_t)(n0 + ty + i) * DM + k0 + tx] = f2b(t[tx][ty + i]);
}

// ---- kernel 3: fused QKV GEMM, 128x128 tile, BK=32, 4 waves.
// 2D grid dim3(24,64), natural dispatch (x fastest): each XCD keeps ~3 B-panels
// L2-resident (R4's 57 MB fetch); the "smart" XCD swizzle thrashed L2 (84 MB,
// +9 us) -- reverted. BN=128 | 1024 -> each block uniformly Q, K, or V.
// Q/K scatter to [B,H,S,HD]; V blocks transpose via LDS, store V^T [bh][hd][s]. ----
__global__ __launch_bounds__(256) void k_gemm(const u16* __restrict__ Xb, const u16* __restrict__ Wt_all,
                                              u16* __restrict__ Out_all, u16* __restrict__ Vt,
                                              float qscale) {
  __shared__ __attribute__((aligned(16))) u16 smem[128 * TSTR];  // 34.8 KB (union)
  u16* At = smem;          // 128x32 = 4096 u16
  u16* Bt = smem + 4096;   // 128x32
  int bx = blockIdx.x, by = blockIdx.y;
  int n0g = bx * 128, m0 = by * 128;
  int which = n0g >> 10;              // uniform per block (128 | 1024)
  int n0 = n0g & 1023;
  int tid = threadIdx.x;
  int lane = tid & 63, w = tid >> 6;
  int l15 = lane & 15, lg = lane >> 4;
  int wm = w >> 1, wn = w & 1;        // 2x2 waves, wave tile 64x64

  const u16* Ag = Xb + (size_t)m0 * DM;
  const u16* Bg = Wt_all + (size_t)n0g * DM;

  f32x4 acc[4][4] = {};
  for (int kt = 0; kt < 32; ++kt) {
    int kk = kt * 32;
    stage_tile32(Ag + kk, At, tid);
    stage_tile32(Bg + kk, Bt, tid);
    __syncthreads();
    bf16x8 af[4], bfr[4];
#pragma unroll
    for (int mi = 0; mi < 4; ++mi)
      af[mi] = ld_swz32(At, wm * 64 + mi * 16 + l15, lg);
#pragma unroll
    for (int ni = 0; ni < 4; ++ni)
      bfr[ni] = ld_swz32(Bt, wn * 64 + ni * 16 + l15, lg);
#pragma unroll
    for (int mi = 0; mi < 4; ++mi)
#pragma unroll
      for (int ni = 0; ni < 4; ++ni)
        acc[mi][ni] = __builtin_amdgcn_mfma_f32_16x16x32_bf16(af[mi], bfr[ni], acc[mi][ni], 0, 0, 0);
    __syncthreads();
  }

  if (which < 2) {
    // Q/K: scatter to [B,H,S,HD]; Q pre-scaled
    float scale = (which == 0) ? qscale : 1.0f;
    u16* Out = Out_all + (size_t)which * (size_t)(4 * NH * S_LEN * HDIM);
#pragma unroll
    for (int mi = 0; mi < 4; ++mi) {
#pragma unroll
      for (int ni = 0; ni < 4; ++ni) {
#pragma unroll
        for (int r = 0; r < 4; ++r) {
          int m = m0 + wm * 64 + mi * 16 + lg * 4 + r;
          int n = n0 + wn * 64 + ni * 16 + l15;
          int b = m >> 11, s = m & 2047;
          int h = n >> 6, hd = n & 63;
          Out[(((size_t)(b * NH + h)) * S_LEN + s) * HDIM + hd] = f2b(acc[mi][ni][r] * scale);
        }
      }
    }
  } else {
    // V: transpose 128x128 tile via LDS (bf16), store V^T [bh][hd][s] coalesced
    u16* T = smem;  // reuse; safe after final __syncthreads of main loop
#pragma unroll
    for (int mi = 0; mi < 4; ++mi) {
#pragma unroll
      for (int ni = 0; ni < 4; ++ni) {
        ushort4 w4 = make_ushort4(f2b(acc[mi][ni][0]), f2b(acc[mi][ni][1]),
                                  f2b(acc[mi][ni][2]), f2b(acc[mi][ni][3]));
        *reinterpret_cast<ushort4*>(T + (wn * 64 + ni * 16 + l15) * TSTR +
                                    wm * 64 + mi * 16 + lg * 4) = w4;
      }
    }
    __syncthreads();
    int base_h = n0 >> 6;
    int b = m0 >> 11, s0 = m0 & 2047;
#pragma unroll
    for (int pass = 0; pass < 8; ++pass) {
      int row = pass * 16 + (tid >> 4);     // local n
      int col = (tid & 15) * 8;             // local m
      ushort8_t v = *reinterpret_cast<const ushort8_t*>(T + row * TSTR + col);
      int h = base_h + (row >> 6), hd = row & 63;
      *reinterpret_cast<ushort8_t*>(Vt + ((size_t)((b * NH + h) * HDIM + hd)) * S_LEN + s0 + col) = v;
    }
  }
}

// ---- block-cooperative flash strip: 4 waves, same head, lockstep K-tiles.
// K double-buffered (staged 1 ahead), V single-buffered. Counted waits only:
// top vmcnt(4|2) guards K(t) (issued 1 iter ago -> free); pre-PV vmcnt(2|0)
// guards V(t) (covered by QK+softmax); end barrier has NO waitcnt.
// Static-exponent softmax: p = exp2(s) raw (normalization cancels in o/ls). ----
__device__ __forceinline__ void attn_strip(const u16* __restrict__ Qp, const u16* __restrict__ Kp,
                                           const u16* __restrict__ Vp, float* __restrict__ out,
                                           int b, int h, int qbase, int w, int tid, int lane, int nt,
                                           u16 (*Kd)[64 * 64], u16* __restrict__ Vd,
                                           u16* __restrict__ Pw) {
  int l15 = lane & 15, lg = lane >> 4;
  int qrow = qbase + w * 16;
  bf16x8 qf0 = ld_bf8(Qp + (size_t)(qrow + l15) * HDIM + lg * 8);
  bf16x8 qf1 = ld_bf8(Qp + (size_t)(qrow + l15) * HDIM + 32 + lg * 8);
  f32x4 o[4] = {};
  float ls = 0.f;
  int qa = qrow + l15;

  stage_tile256(Kp, HDIM, Kd[0], tid);
  asm volatile("s_waitcnt vmcnt(0)" ::: "memory");
  __builtin_amdgcn_sched_barrier(0);
  __builtin_amdgcn_s_barrier();
  __builtin_amdgcn_sched_barrier(0);

  for (int kt = 0; kt < nt; ++kt) {
    int k0 = kt * 64;
    int cur = kt & 1;
    bool pre = (kt + 1 < nt);
    stage_tile256(Vp + k0, S_LEN, Vd, tid);
    if (pre) stage_tile256(Kp + (size_t)(k0 + 64) * HDIM, HDIM, Kd[cur ^ 1], tid);

    // top wait: K(t) landed for all waves (outstanding: V(t)=2 [+K(t+1)=2])
    if (pre) asm volatile("s_waitcnt vmcnt(4)" ::: "memory");
    else     asm volatile("s_waitcnt vmcnt(2)" ::: "memory");
    __builtin_amdgcn_sched_barrier(0);
    __builtin_amdgcn_s_barrier();
    __builtin_amdgcn_sched_barrier(0);

    f32x4 sc[4];
    __builtin_amdgcn_s_setprio(1);
#pragma unroll
    for (int kb = 0; kb < 4; ++kb) {
      bf16x8 kf0 = ld_swz64(Kd[cur], kb * 16 + l15, lg);
      bf16x8 kf1 = ld_swz64(Kd[cur], kb * 16 + l15, 4 + lg);
      f32x4 z = {};
      z = __builtin_amdgcn_mfma_f32_16x16x32_bf16(kf0, qf0, z, 0, 0, 0);
      sc[kb] = __builtin_amdgcn_mfma_f32_16x16x32_bf16(kf1, qf1, sc[kb] = z, 0, 0, 0);
    }
    __builtin_amdgcn_s_setprio(0);

    if (kt == nt - 1) {
#pragma unroll
      for (int kb = 0; kb < 4; ++kb) {
        bf16x4_t pw;
#pragma unroll
        for (int r = 0; r < 4; ++r) {
          int key = k0 + kb * 16 + lg * 4 + r;
          float e = __builtin_amdgcn_exp2f(sc[kb][r]);
          e = (key > qa) ? 0.f : e;
          ls += e;
          pw[r] = (bf16_t)e;
        }
        *reinterpret_cast<bf16x4_t*>(Pw + l15 * PSTR + kb * 16 + lg * 4) = pw;
      }
    } else {
#pragma unroll
      for (int kb = 0; kb < 4; ++kb) {
        bf16x4_t pw;
#pragma unroll
        for (int r = 0; r < 4; ++r) {
          float e = __builtin_amdgcn_exp2f(sc[kb][r]);
          ls += e;
          pw[r] = (bf16_t)e;
        }
        *reinterpret_cast<bf16x4_t*>(Pw + l15 * PSTR + kb * 16 + lg * 4) = pw;
      }
    }
    asm volatile("" ::: "memory");  // P write->read order (per-wave, DS in-order)
    bf16x8 pf0 = ld_bf8(Pw + l15 * PSTR + lg * 8);
    bf16x8 pf1 = ld_bf8(Pw + l15 * PSTR + 32 + lg * 8);

    // pre-PV wait: V(t) landed (outstanding after: K(t+1) only)
    if (pre) asm volatile("s_waitcnt vmcnt(2) lgkmcnt(0)" ::: "memory");
    else     asm volatile("s_waitcnt vmcnt(0) lgkmcnt(0)" ::: "memory");
    __builtin_amdgcn_sched_barrier(0);
    __builtin_amdgcn_s_barrier();
    __builtin_amdgcn_sched_barrier(0);

    __builtin_amdgcn_s_setprio(1);
#pragma unroll
    for (int n = 0; n < 4; ++n) {
      bf16x8 vf0 = ld_swz64(Vd, n * 16 + l15, lg);
      bf16x8 vf1 = ld_swz64(Vd, n * 16 + l15, 4 + lg);
      o[n] = __builtin_amdgcn_mfma_f32_16x16x32_bf16(pf0, vf0, o[n], 0, 0, 0);
      o[n] = __builtin_amdgcn_mfma_f32_16x16x32_bf16(pf1, vf1, o[n], 0, 0, 0);
    }
    __builtin_amdgcn_s_setprio(0);

    // end barrier (no waitcnt): protects Vd overwrite by next iter's stage
    __builtin_amdgcn_sched_barrier(0);
    __builtin_amdgcn_s_barrier();
    __builtin_amdgcn_sched_barrier(0);
  }

  ls += __shfl_xor(ls, 16);
  ls += __shfl_xor(ls, 32);
  float l0 = __shfl(ls, lg * 4 + 0);
  float l1 = __shfl(ls, lg * 4 + 1);
  float l2 = __shfl(ls, lg * 4 + 2);
  float l3 = __shfl(ls, lg * 4 + 3);
  float lsr[4] = {l0, l1, l2, l3};
#pragma unroll
  for (int r = 0; r < 4; ++r) {
    float inv = 1.f / lsr[r];
    int row = qrow + lg * 4 + r;
#pragma unroll
    for (int n = 0; n < 4; ++n)
      out[((size_t)b * S_LEN + row) * DM + h * HDIM + n * 16 + l15] = o[n][r] * inv;
  }
}

// ---- kernel 5: causal flash attention ----
__global__ __launch_bounds__(256, 4) void k_attn(const u16* __restrict__ Qb, const u16* __restrict__ Kb,
                                                 const u16* __restrict__ Vtb, float* __restrict__ out) {
  __shared__ u16 Kd[2][64 * 64];
  __shared__ u16 Vd[64 * 64];
  __shared__ u16 Plds[4][16 * PSTR];
  int j = blockIdx.x;
  int m = j >> 3;
  int x = m & 15;
  int bh = (j & 7) + 8 * (m >> 4);
  int tid = threadIdx.x, lane = tid & 63, w = tid >> 6;
  int b = bh >> 4, h = bh & 15;
  const u16* Qp = Qb + (size_t)bh * S_LEN * HDIM;
  const u16* Kp = Kb + (size_t)bh * S_LEN * HDIM;
  const u16* Vp = Vtb + (size_t)bh * HDIM * S_LEN;
  u16* Pw = Plds[w];
  attn_strip(Qp, Kp, Vp, out, b, h, x * 64, w, tid, lane, x + 1, Kd, Vd, Pw);
  attn_strip(Qp, Kp, Vp, out, b, h, (31 - x) * 64, w, tid, lane, 32 - x, Kd, Vd, Pw);
}

extern "C" void kernel_launch(void* const* d_in, const int* in_sizes, int n_in,
                              void* d_out, int out_size, void* d_ws, size_t ws_size,
                              hipStream_t stream) {
  const float* x  = (const float*)d_in[0];
  const float* Wq = (const float*)d_in[1];
  const float* Wk = (const float*)d_in[2];
  const float* Wv = (const float*)d_in[3];
  float* out = (float*)d_out;

  u16* ws  = (u16*)d_ws;
  u16* xb  = ws;                    // 8192*1024
  u16* wqt = xb + 8388608;          // 3 x 1024*1024 contiguous
  u16* wkt = wqt + 1048576;
  u16* wvt = wkt + 1048576;
  u16* Qb  = wvt + 1048576;         // Q,K each [B,H,S,HD]
  u16* Kb  = Qb + 8388608;
  u16* Vtb = Kb + 8388608;          // [B,H,HD,S] written directly by k_gemm

  const float qscale = 0.125f * 1.44269504088896f;  // 1/sqrt(64) * log2(e)

  k_cvt<<<8192, 256, 0, stream>>>(x, xb);
  k_wt<<<dim3(32, 32), 256, 0, stream>>>(Wq, wqt);
  k_wt<<<dim3(32, 32), 256, 0, stream>>>(Wk, wkt);
  k_wt<<<dim3(32, 32), 256, 0, stream>>>(Wv, wvt);
  k_gemm<<<dim3(24, 64), 256, 0, stream>>>(xb, wqt, Qb, Vtb, qscale);
  k_attn<<<1024, 256, 0, stream>>>(Qb, Kb, Vtb, out);
}

// Round 10
// 141.606 us; speedup vs baseline: 1.0298x; 1.0298x over previous
//
#include <hip/hip_runtime.h>

typedef unsigned short u16;
typedef unsigned int u32;
typedef __bf16 bf16_t;
typedef bf16_t bf16x8 __attribute__((ext_vector_type(8)));
typedef bf16_t bf16x4_t __attribute__((ext_vector_type(4)));
typedef float f32x4 __attribute__((ext_vector_type(4)));
typedef unsigned short ushort8_t __attribute__((ext_vector_type(8)));

#define S_LEN 2048
#define DM 1024
#define NH 16
#define HDIM 64
#define PSTR 80   // attn P row stride in u16
#define TSTR 136  // epilogue-transpose LDS row stride in u16 (272B: 16B-aligned, ~2-way max)

// ---- helpers ----
__device__ __forceinline__ u16 f2b(float f) {
  u32 u = __builtin_bit_cast(u32, f);
  u32 r = (u + 0x7FFFu + ((u >> 16) & 1u)) >> 16;  // RNE
  return (u16)r;
}

__device__ __forceinline__ void gload16(const void* g, void* l) {
  __builtin_amdgcn_global_load_lds((const __attribute__((address_space(1))) void*)g,
                                   (__attribute__((address_space(3))) void*)l,
                                   16, 0, 0);
}

__device__ __forceinline__ bf16x8 ld_bf8(const u16* p) {
  return *reinterpret_cast<const bf16x8*>(p);
}

// ---- 64x64 tile staging for attn (row stride `stride` u16), source-swizzled ----
__device__ __forceinline__ void stage_tile256(const u16* __restrict__ base, int stride,
                                              u16* __restrict__ dst, int tid) {
#pragma unroll
  for (int i = 0; i < 2; ++i) {
    int ci = i * 256 + tid;
    int row = ci >> 3, col = ci & 7;
    gload16(base + (size_t)row * stride + ((col ^ (row & 7)) << 3), dst + ci * 8);
  }
}
__device__ __forceinline__ bf16x8 ld_swz64(const u16* lds, int row, int chunk) {
  return ld_bf8(lds + row * 64 + ((chunk ^ (row & 7)) << 3));
}

// ---- 128x32 tile staging for GEMM (64B rows, 4 chunks; swz f(row)=(row>>1)&3) ----
__device__ __forceinline__ void stage_tile32(const u16* __restrict__ base,
                                             u16* __restrict__ dst, int tid) {
#pragma unroll
  for (int i = 0; i < 2; ++i) {
    int ci = i * 256 + tid;
    int row = ci >> 2, ch = ci & 3;
    gload16(base + (size_t)row * DM + ((ch ^ ((row >> 1) & 3)) << 3), dst + ci * 8);
  }
}
__device__ __forceinline__ bf16x8 ld_swz32(const u16* lds, int row, int chunk) {
  return ld_bf8(lds + row * 32 + ((chunk ^ ((row >> 1) & 3)) << 3));
}

// ---- kernel 1: x f32 -> bf16 ----
__global__ __launch_bounds__(256) void k_cvt(const float* __restrict__ in, u16* __restrict__ out) {
  int i = (blockIdx.x * 256 + threadIdx.x) * 4;
  float4 v = *reinterpret_cast<const float4*>(in + i);
  ushort4 o = make_ushort4(f2b(v.x), f2b(v.y), f2b(v.z), f2b(v.w));
  *reinterpret_cast<ushort4*>(out + i) = o;
}

// ---- kernel 2: all three W [K][N] f32 -> Wt [3*N][K] bf16 in one launch ----
__global__ __launch_bounds__(256) void k_wt3(const float* __restrict__ Wq, const float* __restrict__ Wk,
                                             const float* __restrict__ Wv, u16* __restrict__ Wt) {
  __shared__ float t[32][33];
  const float* W = (blockIdx.z == 0) ? Wq : (blockIdx.z == 1) ? Wk : Wv;
  u16* dst = Wt + (size_t)blockIdx.z * (DM * DM);
  int n0 = blockIdx.x * 32, k0 = blockIdx.y * 32;
  int tx = threadIdx.x & 31, ty = threadIdx.x >> 5;
#pragma unroll
  for (int i = 0; i < 32; i += 8)
    t[ty + i][tx] = W[(size_t)(k0 + ty + i) * DM + n0 + tx];
  __syncthreads();
#pragma unroll
  for (int i = 0; i < 32; i += 8)
    dst[(size_t)(n0 + ty + i) * DM + k0 + tx] = f2b(t[tx][ty + i]);
}

// ---- kernel 3: fused QKV GEMM, 128x128 tile, BK=32, 4 waves, 2D natural grid.
// Q/K blocks compute C^T in registers (mfma(B,A): thread's 4 accs contiguous in n)
// -> LDS transpose -> fully coalesced b128 row stores of [s][hd].
// V blocks compute C (mfma(A,B): accs contiguous in m) -> LDS transpose ->
// coalesced V^T [bh][hd][s] stores. No scalar global stores anywhere. ----
__global__ __launch_bounds__(256) void k_gemm(const u16* __restrict__ Xb, const u16* __restrict__ Wt_all,
                                              u16* __restrict__ Out_all, u16* __restrict__ Vt,
                                              float qscale) {
  __shared__ __attribute__((aligned(16))) u16 smem[128 * TSTR];  // 34.8 KB (union)
  u16* At = smem;          // 128x32 = 4096 u16
  u16* Bt = smem + 4096;   // 128x32
  int bx = blockIdx.x, by = blockIdx.y;
  int n0g = bx * 128, m0 = by * 128;
  int which = n0g >> 10;              // uniform per block (128 | 1024)
  int n0 = n0g & 1023;
  int tid = threadIdx.x;
  int lane = tid & 63, w = tid >> 6;
  int l15 = lane & 15, lg = lane >> 4;
  int wm = w >> 1, wn = w & 1;        // 2x2 waves, wave tile 64x64

  const u16* Ag = Xb + (size_t)m0 * DM;
  const u16* Bg = Wt_all + (size_t)n0g * DM;

  f32x4 acc[4][4] = {};
  for (int kt = 0; kt < 32; ++kt) {
    int kk = kt * 32;
    stage_tile32(Ag + kk, At, tid);
    stage_tile32(Bg + kk, Bt, tid);
    __syncthreads();
    bf16x8 af[4], bfr[4];
#pragma unroll
    for (int mi = 0; mi < 4; ++mi)
      af[mi] = ld_swz32(At, wm * 64 + mi * 16 + l15, lg);
#pragma unroll
    for (int ni = 0; ni < 4; ++ni)
      bfr[ni] = ld_swz32(Bt, wn * 64 + ni * 16 + l15, lg);
    if (which < 2) {
      // transposed: acc[mi][ni] rows = n (lg*4+r), col = m (l15)
#pragma unroll
      for (int mi = 0; mi < 4; ++mi)
#pragma unroll
        for (int ni = 0; ni < 4; ++ni)
          acc[mi][ni] = __builtin_amdgcn_mfma_f32_16x16x32_bf16(bfr[ni], af[mi], acc[mi][ni], 0, 0, 0);
    } else {
      // normal: acc[mi][ni] rows = m (lg*4+r), col = n (l15)
#pragma unroll
      for (int mi = 0; mi < 4; ++mi)
#pragma unroll
        for (int ni = 0; ni < 4; ++ni)
          acc[mi][ni] = __builtin_amdgcn_mfma_f32_16x16x32_bf16(af[mi], bfr[ni], acc[mi][ni], 0, 0, 0);
    }
    __syncthreads();
  }

  u16* T = smem;  // reuse; safe after final __syncthreads of main loop
  int b = m0 >> 11, s0 = m0 & 2047;
  if (which < 2) {
    // Q/K: thread holds 4 contiguous n at fixed m=l15 -> LDS [m][n] tile via b64
    float scale = (which == 0) ? qscale : 1.0f;
    u16* Out = Out_all + (size_t)which * (size_t)(4 * NH * S_LEN * HDIM);
#pragma unroll
    for (int mi = 0; mi < 4; ++mi) {
#pragma unroll
      for (int ni = 0; ni < 4; ++ni) {
        ushort4 w4 = make_ushort4(f2b(acc[mi][ni][0] * scale), f2b(acc[mi][ni][1] * scale),
                                  f2b(acc[mi][ni][2] * scale), f2b(acc[mi][ni][3] * scale));
        *reinterpret_cast<ushort4*>(T + (wm * 64 + mi * 16 + l15) * TSTR +
                                    wn * 64 + ni * 16 + lg * 4) = w4;
      }
    }
    __syncthreads();
    int base_h = n0 >> 6;
#pragma unroll
    for (int pass = 0; pass < 8; ++pass) {
      int row = pass * 16 + (tid >> 4);     // m_local (s offset)
      int col = (tid & 15) * 8;             // n_local chunk (stays within one head)
      ushort8_t v = *reinterpret_cast<const ushort8_t*>(T + row * TSTR + col);
      int h = base_h + (col >> 6), hd = col & 63;
      *reinterpret_cast<ushort8_t*>(Out + ((size_t)(b * NH + h) * S_LEN + s0 + row) * HDIM + hd) = v;
    }
  } else {
    // V: thread holds 4 contiguous m at fixed n=l15 -> LDS [n][m] tile via b64
#pragma unroll
    for (int mi = 0; mi < 4; ++mi) {
#pragma unroll
      for (int ni = 0; ni < 4; ++ni) {
        ushort4 w4 = make_ushort4(f2b(acc[mi][ni][0]), f2b(acc[mi][ni][1]),
                                  f2b(acc[mi][ni][2]), f2b(acc[mi][ni][3]));
        *reinterpret_cast<ushort4*>(T + (wn * 64 + ni * 16 + l15) * TSTR +
                                    wm * 64 + mi * 16 + lg * 4) = w4;
      }
    }
    __syncthreads();
    int base_h = n0 >> 6;
#pragma unroll
    for (int pass = 0; pass < 8; ++pass) {
      int row = pass * 16 + (tid >> 4);     // n_local (hd)
      int col = (tid & 15) * 8;             // m_local chunk (s offset)
      ushort8_t v = *reinterpret_cast<const ushort8_t*>(T + row * TSTR + col);
      int h = base_h + (row >> 6), hd = row & 63;
      *reinterpret_cast<ushort8_t*>(Vt + ((size_t)((b * NH + h) * HDIM + hd)) * S_LEN + s0 + col) = v;
    }
  }
}

// ---- block-cooperative flash strip: 4 waves, same head, lockstep K-tiles.
// K double-buffered (staged 1 ahead), V single-buffered. Counted waits only.
// Static-exponent softmax: p = exp2(s) raw (normalization cancels in o/ls). ----
__device__ __forceinline__ void attn_strip(const u16* __restrict__ Qp, const u16* __restrict__ Kp,
                                           const u16* __restrict__ Vp, float* __restrict__ out,
                                           int b, int h, int qbase, int w, int tid, int lane, int nt,
                                           u16 (*Kd)[64 * 64], u16* __restrict__ Vd,
                                           u16* __restrict__ Pw) {
  int l15 = lane & 15, lg = lane >> 4;
  int qrow = qbase + w * 16;
  bf16x8 qf0 = ld_bf8(Qp + (size_t)(qrow + l15) * HDIM + lg * 8);
  bf16x8 qf1 = ld_bf8(Qp + (size_t)(qrow + l15) * HDIM + 32 + lg * 8);
  f32x4 o[4] = {};
  float ls = 0.f;
  int qa = qrow + l15;

  stage_tile256(Kp, HDIM, Kd[0], tid);
  asm volatile("s_waitcnt vmcnt(0)" ::: "memory");
  __builtin_amdgcn_sched_barrier(0);
  __builtin_amdgcn_s_barrier();
  __builtin_amdgcn_sched_barrier(0);

  for (int kt = 0; kt < nt; ++kt) {
    int k0 = kt * 64;
    int cur = kt & 1;
    bool pre = (kt + 1 < nt);
    stage_tile256(Vp + k0, S_LEN, Vd, tid);
    if (pre) stage_tile256(Kp + (size_t)(k0 + 64) * HDIM, HDIM, Kd[cur ^ 1], tid);

    // top wait: K(t) landed for all waves (outstanding: V(t)=2 [+K(t+1)=2])
    if (pre) asm volatile("s_waitcnt vmcnt(4)" ::: "memory");
    else     asm volatile("s_waitcnt vmcnt(2)" ::: "memory");
    __builtin_amdgcn_sched_barrier(0);
    __builtin_amdgcn_s_barrier();
    __builtin_amdgcn_sched_barrier(0);

    f32x4 sc[4];
    __builtin_amdgcn_s_setprio(1);
#pragma unroll
    for (int kb = 0; kb < 4; ++kb) {
      bf16x8 kf0 = ld_swz64(Kd[cur], kb * 16 + l15, lg);
      bf16x8 kf1 = ld_swz64(Kd[cur], kb * 16 + l15, 4 + lg);
      f32x4 z = {};
      z = __builtin_amdgcn_mfma_f32_16x16x32_bf16(kf0, qf0, z, 0, 0, 0);
      sc[kb] = __builtin_amdgcn_mfma_f32_16x16x32_bf16(kf1, qf1, sc[kb] = z, 0, 0, 0);
    }
    __builtin_amdgcn_s_setprio(0);

    if (kt == nt - 1) {
#pragma unroll
      for (int kb = 0; kb < 4; ++kb) {
        bf16x4_t pw;
#pragma unroll
        for (int r = 0; r < 4; ++r) {
          int key = k0 + kb * 16 + lg * 4 + r;
          float e = __builtin_amdgcn_exp2f(sc[kb][r]);
          e = (key > qa) ? 0.f : e;
          ls += e;
          pw[r] = (bf16_t)e;
        }
        *reinterpret_cast<bf16x4_t*>(Pw + l15 * PSTR + kb * 16 + lg * 4) = pw;
      }
    } else {
#pragma unroll
      for (int kb = 0; kb < 4; ++kb) {
        bf16x4_t pw;
#pragma unroll
        for (int r = 0; r < 4; ++r) {
          float e = __builtin_amdgcn_exp2f(sc[kb][r]);
          ls += e;
          pw[r] = (bf16_t)e;
        }
        *reinterpret_cast<bf16x4_t*>(Pw + l15 * PSTR + kb * 16 + lg * 4) = pw;
      }
    }
    asm volatile("" ::: "memory");  // P write->read order (per-wave, DS in-order)
    bf16x8 pf0 = ld_bf8(Pw + l15 * PSTR + lg * 8);
    bf16x8 pf1 = ld_bf8(Pw + l15 * PSTR + 32 + lg * 8);

    // pre-PV wait: V(t) landed (outstanding after: K(t+1) only)
    if (pre) asm volatile("s_waitcnt vmcnt(2) lgkmcnt(0)" ::: "memory");
    else     asm volatile("s_waitcnt vmcnt(0) lgkmcnt(0)" ::: "memory");
    __builtin_amdgcn_sched_barrier(0);
    __builtin_amdgcn_s_barrier();
    __builtin_amdgcn_sched_barrier(0);

    __builtin_amdgcn_s_setprio(1);
#pragma unroll
    for (int n = 0; n < 4; ++n) {
      bf16x8 vf0 = ld_swz64(Vd, n * 16 + l15, lg);
      bf16x8 vf1 = ld_swz64(Vd, n * 16 + l15, 4 + lg);
      o[n] = __builtin_amdgcn_mfma_f32_16x16x32_bf16(pf0, vf0, o[n], 0, 0, 0);
      o[n] = __builtin_amdgcn_mfma_f32_16x16x32_bf16(pf1, vf1, o[n], 0, 0, 0);
    }
    __builtin_amdgcn_s_setprio(0);

    // end barrier (no waitcnt): protects Vd overwrite by next iter's stage
    __builtin_amdgcn_sched_barrier(0);
    __builtin_amdgcn_s_barrier();
    __builtin_amdgcn_sched_barrier(0);
  }

  ls += __shfl_xor(ls, 16);
  ls += __shfl_xor(ls, 32);
  float l0 = __shfl(ls, lg * 4 + 0);
  float l1 = __shfl(ls, lg * 4 + 1);
  float l2 = __shfl(ls, lg * 4 + 2);
  float l3 = __shfl(ls, lg * 4 + 3);
  float lsr[4] = {l0, l1, l2, l3};
#pragma unroll
  for (int r = 0; r < 4; ++r) {
    float inv = 1.f / lsr[r];
    int row = qrow + lg * 4 + r;
#pragma unroll
    for (int n = 0; n < 4; ++n)
      out[((size_t)b * S_LEN + row) * DM + h * HDIM + n * 16 + l15] = o[n][r] * inv;
  }
}

// ---- kernel 5: causal flash attention ----
__global__ __launch_bounds__(256, 4) void k_attn(const u16* __restrict__ Qb, const u16* __restrict__ Kb,
                                                 const u16* __restrict__ Vtb, float* __restrict__ out) {
  __shared__ u16 Kd[2][64 * 64];
  __shared__ u16 Vd[64 * 64];
  __shared__ u16 Plds[4][16 * PSTR];
  int j = blockIdx.x;
  int m = j >> 3;
  int x = m & 15;
  int bh = (j & 7) + 8 * (m >> 4);
  int tid = threadIdx.x, lane = tid & 63, w = tid >> 6;
  int b = bh >> 4, h = bh & 15;
  const u16* Qp = Qb + (size_t)bh * S_LEN * HDIM;
  const u16* Kp = Kb + (size_t)bh * S_LEN * HDIM;
  const u16* Vp = Vtb + (size_t)bh * HDIM * S_LEN;
  u16* Pw = Plds[w];
  attn_strip(Qp, Kp, Vp, out, b, h, x * 64, w, tid, lane, x + 1, Kd, Vd, Pw);
  attn_strip(Qp, Kp, Vp, out, b, h, (31 - x) * 64, w, tid, lane, 32 - x, Kd, Vd, Pw);
}

extern "C" void kernel_launch(void* const* d_in, const int* in_sizes, int n_in,
                              void* d_out, int out_size, void* d_ws, size_t ws_size,
                              hipStream_t stream) {
  const float* x  = (const float*)d_in[0];
  const float* Wq = (const float*)d_in[1];
  const float* Wk = (const float*)d_in[2];
  const float* Wv = (const float*)d_in[3];
  float* out = (float*)d_out;

  u16* ws  = (u16*)d_ws;
  u16* xb  = ws;                    // 8192*1024
  u16* wqt = xb + 8388608;          // 3 x 1024*1024 contiguous
  u16* Qb  = wqt + 3145728;         // Q,K each [B,H,S,HD]
  u16* Kb  = Qb + 8388608;
  u16* Vtb = Kb + 8388608;          // [B,H,HD,S] written directly by k_gemm

  const float qscale = 0.125f * 1.44269504088896f;  // 1/sqrt(64) * log2(e)

  k_cvt<<<8192, 256, 0, stream>>>(x, xb);
  k_wt3<<<dim3(32, 32, 3), 256, 0, stream>>>(Wq, Wk, Wv, wqt);
  k_gemm<<<dim3(24, 64), 256, 0, stream>>>(xb, wqt, Qb, Vtb, qscale);
  k_attn<<<1024, 256, 0, stream>>>(Qb, Kb, Vtb, out);
}

// Round 11
// 137.593 us; speedup vs baseline: 1.0598x; 1.0292x over previous
//
#include <hip/hip_runtime.h>

typedef unsigned short u16;
typedef unsigned int u32;
typedef __bf16 bf16_t;
typedef bf16_t bf16x8 __attribute__((ext_vector_type(8)));
typedef bf16_t bf16x4_t __attribute__((ext_vector_type(4)));
typedef float f32x4 __attribute__((ext_vector_type(4)));
typedef unsigned short ushort8_t __attribute__((ext_vector_type(8)));

#define S_LEN 2048
#define DM 1024
#define NH 16
#define HDIM 64
#define PSTR 80   // attn P row stride in u16
#define TSTR 136  // epilogue-transpose LDS row stride in u16

// ---- helpers ----
__device__ __forceinline__ u16 f2b(float f) {
  u32 u = __builtin_bit_cast(u32, f);
  u32 r = (u + 0x7FFFu + ((u >> 16) & 1u)) >> 16;  // RNE
  return (u16)r;
}

__device__ __forceinline__ void gload16(const void* g, void* l) {
  __builtin_amdgcn_global_load_lds((const __attribute__((address_space(1))) void*)g,
                                   (__attribute__((address_space(3))) void*)l,
                                   16, 0, 0);
}

__device__ __forceinline__ bf16x8 ld_bf8(const u16* p) {
  return *reinterpret_cast<const bf16x8*>(p);
}

// ---- 64x64 tile staging for attn (row stride `stride` u16), source-swizzled
// (load-bearing there: 128B rows -> 16-way conflict without it) ----
__device__ __forceinline__ void stage_tile256(const u16* __restrict__ base, int stride,
                                              u16* __restrict__ dst, int tid) {
#pragma unroll
  for (int i = 0; i < 2; ++i) {
    int ci = i * 256 + tid;
    int row = ci >> 3, col = ci & 7;
    gload16(base + (size_t)row * stride + ((col ^ (row & 7)) << 3), dst + ci * 8);
  }
}
__device__ __forceinline__ bf16x8 ld_swz64(const u16* lds, int row, int chunk) {
  return ld_bf8(lds + row * 64 + ((chunk ^ (row & 7)) << 3));
}

// ---- kernel 1: x f32 -> bf16 ----
__global__ __launch_bounds__(256) void k_cvt(const float* __restrict__ in, u16* __restrict__ out) {
  int i = (blockIdx.x * 256 + threadIdx.x) * 4;
  float4 v = *reinterpret_cast<const float4*>(in + i);
  ushort4 o = make_ushort4(f2b(v.x), f2b(v.y), f2b(v.z), f2b(v.w));
  *reinterpret_cast<ushort4*>(out + i) = o;
}

// ---- kernel 2: all three W [K][N] f32 -> Wt [3*N][K] bf16 in one launch ----
__global__ __launch_bounds__(256) void k_wt3(const float* __restrict__ Wq, const float* __restrict__ Wk,
                                             const float* __restrict__ Wv, u16* __restrict__ Wt) {
  __shared__ float t[32][33];
  const float* W = (blockIdx.z == 0) ? Wq : (blockIdx.z == 1) ? Wk : Wv;
  u16* dst = Wt + (size_t)blockIdx.z * (DM * DM);
  int n0 = blockIdx.x * 32, k0 = blockIdx.y * 32;
  int tx = threadIdx.x & 31, ty = threadIdx.x >> 5;
#pragma unroll
  for (int i = 0; i < 32; i += 8)
    t[ty + i][tx] = W[(size_t)(k0 + ty + i) * DM + n0 + tx];
  __syncthreads();
#pragma unroll
  for (int i = 0; i < 32; i += 8)
    dst[(size_t)(n0 + ty + i) * DM + k0 + tx] = f2b(t[tx][ty + i]);
}

// ---- GEMM core: 32 K-iters, linear LDS staging (R4 layout), single buffer.
// TRANSPOSED: acc = B^T*A-style mfma(bfr, af) so thread's 4 accs contiguous in n. ----
template <bool TRANSPOSED>
__device__ __forceinline__ void gemm_loop(const u16* __restrict__ Ag, const u16* __restrict__ Bg,
                                          u16* __restrict__ At, u16* __restrict__ Bt,
                                          f32x4 (&acc)[4][4], int tid, int l15, int lg,
                                          int wm, int wn) {
  for (int kt = 0; kt < 32; ++kt) {
    int kk = kt * 32;
#pragma unroll
    for (int i = 0; i < 2; ++i) {
      int t2 = i * 256 + tid;
      int row = t2 >> 2, c = t2 & 3;
      gload16(Ag + (size_t)row * DM + kk + c * 8, At + t2 * 8);
      gload16(Bg + (size_t)row * DM + kk + c * 8, Bt + t2 * 8);
    }
    __syncthreads();
    bf16x8 af[4], bfr[4];
#pragma unroll
    for (int mi = 0; mi < 4; ++mi)
      af[mi] = ld_bf8(At + (wm * 64 + mi * 16 + l15) * 32 + lg * 8);
#pragma unroll
    for (int ni = 0; ni < 4; ++ni)
      bfr[ni] = ld_bf8(Bt + (wn * 64 + ni * 16 + l15) * 32 + lg * 8);
#pragma unroll
    for (int mi = 0; mi < 4; ++mi)
#pragma unroll
      for (int ni = 0; ni < 4; ++ni) {
        if (TRANSPOSED)
          acc[mi][ni] = __builtin_amdgcn_mfma_f32_16x16x32_bf16(bfr[ni], af[mi], acc[mi][ni], 0, 0, 0);
        else
          acc[mi][ni] = __builtin_amdgcn_mfma_f32_16x16x32_bf16(af[mi], bfr[ni], acc[mi][ni], 0, 0, 0);
      }
    __syncthreads();
  }
}

// ---- kernel 3: fused QKV GEMM, 128x128 tile, BK=32, 4 waves, 2D natural grid.
// __launch_bounds__(256,3): cap regs so 3 waves/SIMD fit (R4's 30% occupancy —
// the 85us variants lost a wave/SIMD to VGPR creep). Q/K: C^T in regs -> LDS
// transpose -> coalesced [s][hd] b128 stores. V: C -> LDS transpose -> V^T. ----
__global__ __launch_bounds__(256, 3) void k_gemm(const u16* __restrict__ Xb, const u16* __restrict__ Wt_all,
                                                 u16* __restrict__ Out_all, u16* __restrict__ Vt,
                                                 float qscale) {
  __shared__ __attribute__((aligned(16))) u16 smem[128 * TSTR];  // 34.8 KB (union)
  u16* At = smem;          // 128x32
  u16* Bt = smem + 4096;   // 128x32
  int bx = blockIdx.x, by = blockIdx.y;
  int n0g = bx * 128, m0 = by * 128;
  int which = n0g >> 10;              // uniform per block (128 | 1024)
  int n0 = n0g & 1023;
  int tid = threadIdx.x;
  int lane = tid & 63, w = tid >> 6;
  int l15 = lane & 15, lg = lane >> 4;
  int wm = w >> 1, wn = w & 1;        // 2x2 waves, wave tile 64x64

  const u16* Ag = Xb + (size_t)m0 * DM;
  const u16* Bg = Wt_all + (size_t)n0g * DM;

  f32x4 acc[4][4] = {};
  u16* T = smem;
  int b = m0 >> 11, s0 = m0 & 2047;
  int base_h = n0 >> 6;

  if (which < 2) {
    gemm_loop<true>(Ag, Bg, At, Bt, acc, tid, l15, lg, wm, wn);
    // Q/K: thread holds 4 contiguous n at fixed m=l15 -> LDS [m][n] tile via b64
    float scale = (which == 0) ? qscale : 1.0f;
    u16* Out = Out_all + (size_t)which * (size_t)(4 * NH * S_LEN * HDIM);
#pragma unroll
    for (int mi = 0; mi < 4; ++mi) {
#pragma unroll
      for (int ni = 0; ni < 4; ++ni) {
        ushort4 w4 = make_ushort4(f2b(acc[mi][ni][0] * scale), f2b(acc[mi][ni][1] * scale),
                                  f2b(acc[mi][ni][2] * scale), f2b(acc[mi][ni][3] * scale));
        *reinterpret_cast<ushort4*>(T + (wm * 64 + mi * 16 + l15) * TSTR +
                                    wn * 64 + ni * 16 + lg * 4) = w4;
      }
    }
    __syncthreads();
#pragma unroll
    for (int pass = 0; pass < 8; ++pass) {
      int row = pass * 16 + (tid >> 4);     // m_local (s offset)
      int col = (tid & 15) * 8;             // n_local chunk (within one head)
      ushort8_t v = *reinterpret_cast<const ushort8_t*>(T + row * TSTR + col);
      int h = base_h + (col >> 6), hd = col & 63;
      *reinterpret_cast<ushort8_t*>(Out + ((size_t)(b * NH + h) * S_LEN + s0 + row) * HDIM + hd) = v;
    }
  } else {
    gemm_loop<false>(Ag, Bg, At, Bt, acc, tid, l15, lg, wm, wn);
    // V: thread holds 4 contiguous m at fixed n=l15 -> LDS [n][m] tile via b64
#pragma unroll
    for (int mi = 0; mi < 4; ++mi) {
#pragma unroll
      for (int ni = 0; ni < 4; ++ni) {
        ushort4 w4 = make_ushort4(f2b(acc[mi][ni][0]), f2b(acc[mi][ni][1]),
                                  f2b(acc[mi][ni][2]), f2b(acc[mi][ni][3]));
        *reinterpret_cast<ushort4*>(T + (wn * 64 + ni * 16 + l15) * TSTR +
                                    wm * 64 + mi * 16 + lg * 4) = w4;
      }
    }
    __syncthreads();
#pragma unroll
    for (int pass = 0; pass < 8; ++pass) {
      int row = pass * 16 + (tid >> 4);     // n_local (hd)
      int col = (tid & 15) * 8;             // m_local chunk (s offset)
      ushort8_t v = *reinterpret_cast<const ushort8_t*>(T + row * TSTR + col);
      int h = base_h + (row >> 6), hd = row & 63;
      *reinterpret_cast<ushort8_t*>(Vt + ((size_t)((b * NH + h) * HDIM + hd)) * S_LEN + s0 + col) = v;
    }
  }
}

// ---- block-cooperative flash strip: 4 waves, same head, lockstep K-tiles.
// K double-buffered (staged 1 ahead), V single-buffered. Counted waits only.
// Static-exponent softmax: p = exp2(s) raw (normalization cancels in o/ls). ----
__device__ __forceinline__ void attn_strip(const u16* __restrict__ Qp, const u16* __restrict__ Kp,
                                           const u16* __restrict__ Vp, float* __restrict__ out,
                                           int b, int h, int qbase, int w, int tid, int lane, int nt,
                                           u16 (*Kd)[64 * 64], u16* __restrict__ Vd,
                                           u16* __restrict__ Pw) {
  int l15 = lane & 15, lg = lane >> 4;
  int qrow = qbase + w * 16;
  bf16x8 qf0 = ld_bf8(Qp + (size_t)(qrow + l15) * HDIM + lg * 8);
  bf16x8 qf1 = ld_bf8(Qp + (size_t)(qrow + l15) * HDIM + 32 + lg * 8);
  f32x4 o[4] = {};
  float ls = 0.f;
  int qa = qrow + l15;

  stage_tile256(Kp, HDIM, Kd[0], tid);
  asm volatile("s_waitcnt vmcnt(0)" ::: "memory");
  __builtin_amdgcn_sched_barrier(0);
  __builtin_amdgcn_s_barrier();
  __builtin_amdgcn_sched_barrier(0);

  for (int kt = 0; kt < nt; ++kt) {
    int k0 = kt * 64;
    int cur = kt & 1;
    bool pre = (kt + 1 < nt);
    stage_tile256(Vp + k0, S_LEN, Vd, tid);
    if (pre) stage_tile256(Kp + (size_t)(k0 + 64) * HDIM, HDIM, Kd[cur ^ 1], tid);

    if (pre) asm volatile("s_waitcnt vmcnt(4)" ::: "memory");
    else     asm volatile("s_waitcnt vmcnt(2)" ::: "memory");
    __builtin_amdgcn_sched_barrier(0);
    __builtin_amdgcn_s_barrier();
    __builtin_amdgcn_sched_barrier(0);

    f32x4 sc[4];
    __builtin_amdgcn_s_setprio(1);
#pragma unroll
    for (int kb = 0; kb < 4; ++kb) {
      bf16x8 kf0 = ld_swz64(Kd[cur], kb * 16 + l15, lg);
      bf16x8 kf1 = ld_swz64(Kd[cur], kb * 16 + l15, 4 + lg);
      f32x4 z = {};
      z = __builtin_amdgcn_mfma_f32_16x16x32_bf16(kf0, qf0, z, 0, 0, 0);
      sc[kb] = __builtin_amdgcn_mfma_f32_16x16x32_bf16(kf1, qf1, sc[kb] = z, 0, 0, 0);
    }
    __builtin_amdgcn_s_setprio(0);

    if (kt == nt - 1) {
#pragma unroll
      for (int kb = 0; kb < 4; ++kb) {
        bf16x4_t pw;
#pragma unroll
        for (int r = 0; r < 4; ++r) {
          int key = k0 + kb * 16 + lg * 4 + r;
          float e = __builtin_amdgcn_exp2f(sc[kb][r]);
          e = (key > qa) ? 0.f : e;
          ls += e;
          pw[r] = (bf16_t)e;
        }
        *reinterpret_cast<bf16x4_t*>(Pw + l15 * PSTR + kb * 16 + lg * 4) = pw;
      }
    } else {
#pragma unroll
      for (int kb = 0; kb < 4; ++kb) {
        bf16x4_t pw;
#pragma unroll
        for (int r = 0; r < 4; ++r) {
          float e = __builtin_amdgcn_exp2f(sc[kb][r]);
          ls += e;
          pw[r] = (bf16_t)e;
        }
        *reinterpret_cast<bf16x4_t*>(Pw + l15 * PSTR + kb * 16 + lg * 4) = pw;
      }
    }
    asm volatile("" ::: "memory");
    bf16x8 pf0 = ld_bf8(Pw + l15 * PSTR + lg * 8);
    bf16x8 pf1 = ld_bf8(Pw + l15 * PSTR + 32 + lg * 8);

    if (pre) asm volatile("s_waitcnt vmcnt(2) lgkmcnt(0)" ::: "memory");
    else     asm volatile("s_waitcnt vmcnt(0) lgkmcnt(0)" ::: "memory");
    __builtin_amdgcn_sched_barrier(0);
    __builtin_amdgcn_s_barrier();
    __builtin_amdgcn_sched_barrier(0);

    __builtin_amdgcn_s_setprio(1);
#pragma unroll
    for (int n = 0; n < 4; ++n) {
      bf16x8 vf0 = ld_swz64(Vd, n * 16 + l15, lg);
      bf16x8 vf1 = ld_swz64(Vd, n * 16 + l15, 4 + lg);
      o[n] = __builtin_amdgcn_mfma_f32_16x16x32_bf16(pf0, vf0, o[n], 0, 0, 0);
      o[n] = __builtin_amdgcn_mfma_f32_16x16x32_bf16(pf1, vf1, o[n], 0, 0, 0);
    }
    __builtin_amdgcn_s_setprio(0);

    __builtin_amdgcn_sched_barrier(0);
    __builtin_amdgcn_s_barrier();
    __builtin_amdgcn_sched_barrier(0);
  }

  ls += __shfl_xor(ls, 16);
  ls += __shfl_xor(ls, 32);
  float l0 = __shfl(ls, lg * 4 + 0);
  float l1 = __shfl(ls, lg * 4 + 1);
  float l2 = __shfl(ls, lg * 4 + 2);
  float l3 = __shfl(ls, lg * 4 + 3);
  float lsr[4] = {l0, l1, l2, l3};
#pragma unroll
  for (int r = 0; r < 4; ++r) {
    float inv = 1.f / lsr[r];
    int row = qrow + lg * 4 + r;
#pragma unroll
    for (int n = 0; n < 4; ++n)
      out[((size_t)b * S_LEN + row) * DM + h * HDIM + n * 16 + l15] = o[n][r] * inv;
  }
}

// ---- kernel 5: causal flash attention ----
__global__ __launch_bounds__(256, 4) void k_attn(const u16* __restrict__ Qb, const u16* __restrict__ Kb,
                                                 const u16* __restrict__ Vtb, float* __restrict__ out) {
  __shared__ u16 Kd[2][64 * 64];
  __shared__ u16 Vd[64 * 64];
  __shared__ u16 Plds[4][16 * PSTR];
  int j = blockIdx.x;
  int m = j >> 3;
  int x = m & 15;
  int bh = (j & 7) + 8 * (m >> 4);
  int tid = threadIdx.x, lane = tid & 63, w = tid >> 6;
  int b = bh >> 4, h = bh & 15;
  const u16* Qp = Qb + (size_t)bh * S_LEN * HDIM;
  const u16* Kp = Kb + (size_t)bh * S_LEN * HDIM;
  const u16* Vp = Vtb + (size_t)bh * HDIM * S_LEN;
  u16* Pw = Plds[w];
  attn_strip(Qp, Kp, Vp, out, b, h, x * 64, w, tid, lane, x + 1, Kd, Vd, Pw);
  attn_strip(Qp, Kp, Vp, out, b, h, (31 - x) * 64, w, tid, lane, 32 - x, Kd, Vd, Pw);
}

extern "C" void kernel_launch(void* const* d_in, const int* in_sizes, int n_in,
                              void* d_out, int out_size, void* d_ws, size_t ws_size,
                              hipStream_t stream) {
  const float* x  = (const float*)d_in[0];
  const float* Wq = (const float*)d_in[1];
  const float* Wk = (const float*)d_in[2];
  const float* Wv = (const float*)d_in[3];
  float* out = (float*)d_out;

  u16* ws  = (u16*)d_ws;
  u16* xb  = ws;                    // 8192*1024
  u16* wqt = xb + 8388608;          // 3 x 1024*1024 contiguous
  u16* Qb  = wqt + 3145728;         // Q,K each [B,H,S,HD]
  u16* Kb  = Qb + 8388608;
  u16* Vtb = Kb + 8388608;          // [B,H,HD,S] written directly by k_gemm

  const float qscale = 0.125f * 1.44269504088896f;  // 1/sqrt(64) * log2(e)

  k_cvt<<<8192, 256, 0, stream>>>(x, xb);
  k_wt3<<<dim3(32, 32, 3), 256, 0, stream>>>(Wq, Wk, Wv, wqt);
  k_gemm<<<dim3(24, 64), 256, 0, stream>>>(xb, wqt, Qb, Vtb, qscale);
  k_attn<<<1024, 256, 0, stream>>>(Qb, Kb, Vtb, out);
}